// Round 4
// baseline (134.782 us; speedup 1.0000x reference)
//
#include <hip/hip_runtime.h>
#include <hip/hip_bf16.h>

#define K1 16
#define NC 32
#define NP 4096
#define NB 16
#define NE (NP * K1)

typedef __attribute__((ext_vector_type(8))) short bf16x8;
typedef __attribute__((ext_vector_type(4))) float f32x4;

__device__ __forceinline__ float bf2f(short u) {
    union { unsigned int i; float f; } x;
    x.i = ((unsigned int)(unsigned short)u) << 16;
    return x.f;
}
__device__ __forceinline__ short f2bf(float f) {
    return (short)__bfloat16_as_ushort(__float2bfloat16(f));
}
__device__ __forceinline__ float relu_f(float x) { return x > 0.f ? x : 0.f; }

// k-slot permutation: hardware slot (g,e) holds logical channel kappa(g,e).
// Chosen so a D-fragment (lane owns rows {g*4+i} of two 16-row o-tiles) is
// directly the next layer's A/B fragment with NO cross-lane movement.
__device__ __forceinline__ int kappa(int g, int e) {
    return (e < 4) ? (g * 4 + e) : (16 + g * 4 + (e - 4));
}

// ---- prep: LDS-tiled transpose to kappa-order bf16 + BN-folded weights ----
// blocks 0..511: transpose 128-point tiles; block 512: weight folding.
__global__ __launch_bounds__(256) void prep(
    const float* __restrict__ feat,
    const float* __restrict__ w0, const float* __restrict__ g0,
    const float* __restrict__ w1, const float* __restrict__ g1,
    const float* __restrict__ w2, const float* __restrict__ g2,
    const float* __restrict__ scw, const float* __restrict__ scg,
    short* __restrict__ featTp, short* __restrict__ w0p,
    short* __restrict__ w1p, short* __restrict__ w2p, short* __restrict__ scwp)
{
    const float INVC = 0.9999950000374997f;   // 1/sqrt(1+1e-5)
    const int blk = blockIdx.x;
    if (blk < 512) {
        __shared__ float sF[32][132];          // stride 132 f32: rows 16B-aligned
        const int tid = threadIdx.x;
        const int b   = blk >> 5;
        const int p0  = (blk & 31) << 7;       // 128-point tile
        const float* fb = feat + (size_t)b * NC * NP + p0;

        // phase A: coalesced f32x4 loads, 32 c x 128 p
        #pragma unroll
        for (int i = 0; i < 4; ++i) {
            int id = tid + (i << 8);           // 1024 chunks
            int c = id >> 5, j = id & 31;
            f32x4 v = *(const f32x4*)(fb + c * NP + j * 4);
            *(f32x4*)(&sF[c][j * 4]) = v;
        }
        __syncthreads();

        // phase B: thread = (point, group); pack one bf16x8, coalesced store
        short* dstb = featTp + ((size_t)b * NP + p0) * 32;
        #pragma unroll
        for (int i = 0; i < 2; ++i) {
            int id = tid + (i << 8);           // 512 tasks
            int pl = id >> 2, g = id & 3;
            short o8[8];
            #pragma unroll
            for (int e = 0; e < 8; ++e)
                o8[e] = f2bf(sF[kappa(g, e)][pl]);
            *(bf16x8*)(dstb + pl * 32 + g * 8) = *(const bf16x8*)o8;
        }
    } else {
        const int t = threadIdx.x;
        for (int idx = t; idx < 2048; idx += 256) {        // w0p: (32 o) x (2 kc) x 32
            int o = idx >> 6, rem = idx & 63, kc = rem >> 5, pos = rem & 31;
            int g = pos >> 3, e = pos & 7;
            w0p[idx] = f2bf(w0[o * 64 + kc * 32 + kappa(g, e)] * g0[o] * INVC);
        }
        for (int idx = t; idx < 1024; idx += 256) {        // w1p: 32 x 32
            int o = idx >> 5, pos = idx & 31, g = pos >> 3, e = pos & 7;
            w1p[idx] = f2bf(w1[o * 32 + kappa(g, e)] * g1[o] * INVC);
        }
        for (int idx = t; idx < 2048; idx += 256) {        // w2p: 64 x 32
            int o = idx >> 5, pos = idx & 31, g = pos >> 3, e = pos & 7;
            w2p[idx] = f2bf(w2[o * 32 + kappa(g, e)] * g2[o] * INVC);
        }
        for (int idx = t; idx < 2048; idx += 256) {        // scwp: 64 x 32
            int o = idx >> 5, pos = idx & 31, g = pos >> 3, e = pos & 7;
            scwp[idx] = f2bf(scw[o * 32 + kappa(g, e)] * scg[o] * INVC);
        }
    }
}

// ---- main: register-resident 3-layer chain + shortcut, no barriers ----
__global__ __launch_bounds__(256, 4) void edgeconv_mfma(
    const int* __restrict__ edge, const short* __restrict__ featTp,
    const float* __restrict__ b0, const float* __restrict__ b1,
    const float* __restrict__ b2,
    const short* __restrict__ w0p, const short* __restrict__ w1p,
    const short* __restrict__ w2p, const short* __restrict__ scwp,
    const float* __restrict__ scb, float* __restrict__ out)
{
    __shared__ float sFts[4][16][68];   // [wave][pt][o], padded: conflict-free

    const int tid  = threadIdx.x;
    const int wv   = tid >> 6;
    const int lane = tid & 63;
    const int lr   = lane & 15;
    const int g    = lane >> 4;

    // XCD-contiguous swizzle: 1024 blocks, 8 XCDs, 128 blocks each
    const int bid = blockIdx.x;
    const int swz = (bid & 7) * 128 + (bid >> 3);
    const int b   = swz >> 6;                       // batch
    const int p0w = ((swz & 63) << 6) + wv * 16;    // wave's first point

    // persistent fragments (kappa-ordered weights)
    bf16x8 wA0[2][2], wA1[2], wB2[4];
    #pragma unroll
    for (int nt = 0; nt < 2; ++nt)
        #pragma unroll
        for (int kc = 0; kc < 2; ++kc)
            wA0[nt][kc] = *(const bf16x8*)(w0p + (nt * 16 + lr) * 64 + kc * 32 + g * 8);
    #pragma unroll
    for (int nt = 0; nt < 2; ++nt)
        wA1[nt] = *(const bf16x8*)(w1p + (nt * 16 + lr) * 32 + g * 8);
    #pragma unroll
    for (int nt = 0; nt < 4; ++nt)
        wB2[nt] = *(const bf16x8*)(w2p + (nt * 16 + lr) * 32 + g * 8);

    f32x4 bias0[2] = { *(const f32x4*)(b0 + g * 4), *(const f32x4*)(b0 + 16 + g * 4) };
    f32x4 bias1[2] = { *(const f32x4*)(b1 + g * 4), *(const f32x4*)(b1 + 16 + g * 4) };
    float bc2[4];
    #pragma unroll
    for (int nt = 0; nt < 4; ++nt) bc2[nt] = b2[nt * 16 + lr];

    const int*   eb = edge + (size_t)b * 2 * NE + NE;
    const short* fT = featTp + (size_t)b * NP * 32;

    #pragma unroll 4
    for (int rt = 0; rt < 16; ++rt) {
        const int p = p0w + rt;
        const int q = eb[p * K1 + lr];
        bf16x8 xf0 = *(const bf16x8*)(fT + p * 32 + g * 8);   // fp (uniform over r)
        bf16x8 fq  = *(const bf16x8*)(fT + (size_t)q * 32 + g * 8);
        bf16x8 xd;
        #pragma unroll
        for (int e = 0; e < 8; ++e) xd[e] = f2bf(bf2f(fq[e]) - bf2f(xf0[e]));

        // L0 (swapped): D0[o][r] = W0' * [fp; d]^T
        f32x4 acc0[2] = {{0.f,0.f,0.f,0.f},{0.f,0.f,0.f,0.f}};
        #pragma unroll
        for (int nt = 0; nt < 2; ++nt) {
            acc0[nt] = __builtin_amdgcn_mfma_f32_16x16x32_bf16(wA0[nt][0], xf0, acc0[nt], 0, 0, 0);
            acc0[nt] = __builtin_amdgcn_mfma_f32_16x16x32_bf16(wA0[nt][1], xd,  acc0[nt], 0, 0, 0);
        }
        // D-frag IS the next B-frag in kappa-order: bias+relu+cvt only
        bf16x8 h0;
        #pragma unroll
        for (int e = 0; e < 4; ++e) {
            h0[e]     = f2bf(relu_f(acc0[0][e] + bias0[0][e]));
            h0[e + 4] = f2bf(relu_f(acc0[1][e] + bias0[1][e]));
        }
        // L1 (swapped): D1[o][r]
        f32x4 acc1[2] = {{0.f,0.f,0.f,0.f},{0.f,0.f,0.f,0.f}};
        #pragma unroll
        for (int nt = 0; nt < 2; ++nt)
            acc1[nt] = __builtin_amdgcn_mfma_f32_16x16x32_bf16(wA1[nt], h0, acc1[nt], 0, 0, 0);
        bf16x8 h1;
        #pragma unroll
        for (int e = 0; e < 4; ++e) {
            h1[e]     = f2bf(relu_f(acc1[0][e] + bias1[0][e]));
            h1[e + 4] = f2bf(relu_f(acc1[1][e] + bias1[1][e]));
        }
        // L2 (standard): D2[r][o] — h1-frag doubles as the A operand
        f32x4 acc2[4] = {{0.f,0.f,0.f,0.f},{0.f,0.f,0.f,0.f},{0.f,0.f,0.f,0.f},{0.f,0.f,0.f,0.f}};
        #pragma unroll
        for (int nt = 0; nt < 4; ++nt)
            acc2[nt] = __builtin_amdgcn_mfma_f32_16x16x32_bf16(h1, wB2[nt], acc2[nt], 0, 0, 0);

        // relu + mean over the 16 edges (rows): local 4 + xor16 + xor32
        float f0, f1, f2, f3;
        #pragma unroll
        for (int nt = 0; nt < 4; ++nt) {
            float s = relu_f(acc2[nt][0] + bc2[nt]) + relu_f(acc2[nt][1] + bc2[nt])
                    + relu_f(acc2[nt][2] + bc2[nt]) + relu_f(acc2[nt][3] + bc2[nt]);
            s += __shfl_xor(s, 16, 64);
            s += __shfl_xor(s, 32, 64);
            if (nt == 0) f0 = s; else if (nt == 1) f1 = s; else if (nt == 2) f2 = s; else f3 = s;
        }
        float sel = (g == 0) ? f0 : (g == 1) ? f1 : (g == 2) ? f2 : f3;
        sFts[wv][rt][g * 16 + lr] = sel;   // o = g*16+lr for this lane's g
    }

    // ---- shortcut: one option-1 MFMA set over the wave's 16 points ----
    bf16x8 aS = *(const bf16x8*)(fT + (p0w + lr) * 32 + g * 8);  // rows = points
    bf16x8 wS[4];
    #pragma unroll
    for (int nt = 0; nt < 4; ++nt)
        wS[nt] = *(const bf16x8*)(scwp + (nt * 16 + lr) * 32 + g * 8);
    float scbc[4];
    #pragma unroll
    for (int nt = 0; nt < 4; ++nt) scbc[nt] = scb[nt * 16 + lr];

    f32x4 accS[4] = {{0.f,0.f,0.f,0.f},{0.f,0.f,0.f,0.f},{0.f,0.f,0.f,0.f},{0.f,0.f,0.f,0.f}};
    #pragma unroll
    for (int nt = 0; nt < 4; ++nt)
        accS[nt] = __builtin_amdgcn_mfma_f32_16x16x32_bf16(aS, wS[nt], accS[nt], 0, 0, 0);

    float* ob = out + (size_t)b * 64 * NP;
    #pragma unroll
    for (int nt = 0; nt < 4; ++nt) {
        f32x4 v;
        #pragma unroll
        for (int i = 0; i < 4; ++i) {
            float fts = sFts[wv][g * 4 + i][nt * 16 + lr];
            v[i] = relu_f(accS[nt][i] + scbc[nt] + fts * 0.0625f);
        }
        *(f32x4*)(ob + (nt * 16 + lr) * NP + p0w + g * 4) = v;
    }
}

extern "C" void kernel_launch(void* const* d_in, const int* in_sizes, int n_in,
                              void* d_out, int out_size, void* d_ws, size_t ws_size,
                              hipStream_t stream) {
    const float* feat = (const float*)d_in[1];
    const int*   edge = (const int*)d_in[2];
    const float* w0   = (const float*)d_in[3];
    const float* g0   = (const float*)d_in[4];
    const float* b0   = (const float*)d_in[5];
    const float* w1   = (const float*)d_in[6];
    const float* g1   = (const float*)d_in[7];
    const float* b1   = (const float*)d_in[8];
    const float* w2   = (const float*)d_in[9];
    const float* g2   = (const float*)d_in[10];
    const float* b2   = (const float*)d_in[11];
    const float* scw  = (const float*)d_in[12];
    const float* scg  = (const float*)d_in[13];
    const float* scb  = (const float*)d_in[14];
    float* outp = (float*)d_out;

    char* ws = (char*)d_ws;
    short* featTp = (short*)ws;                 // 16*4096*32*2 = 4,194,304 B
    short* w0p    = (short*)(ws + 4194304);     // 4096 B
    short* w1p    = (short*)(ws + 4198400);     // 2048 B
    short* w2p    = (short*)(ws + 4200448);     // 4096 B
    short* scwp   = (short*)(ws + 4204544);     // 4096 B

    prep<<<513, 256, 0, stream>>>(feat, w0, g0, w1, g1, w2, g2, scw, scg,
                                  featTp, w0p, w1p, w2p, scwp);
    edgeconv_mfma<<<1024, 256, 0, stream>>>(
        edge, featTp, b0, b1, b2, w0p, w1p, w2p, scwp, scb, outp);
}

// Round 5
// 133.373 us; speedup vs baseline: 1.0106x; 1.0106x over previous
//
#include <hip/hip_runtime.h>
#include <hip/hip_bf16.h>

#define K1 16
#define NC 32
#define NP 4096
#define NB 16
#define NE (NP * K1)

typedef __attribute__((ext_vector_type(8))) short bf16x8;
typedef __attribute__((ext_vector_type(4))) float f32x4;

__device__ __forceinline__ float bf2f(short u) {
    union { unsigned int i; float f; } x;
    x.i = ((unsigned int)(unsigned short)u) << 16;
    return x.f;
}
__device__ __forceinline__ short f2bf(float f) {
    return (short)__bfloat16_as_ushort(__float2bfloat16(f));
}
__device__ __forceinline__ float relu_f(float x) { return x > 0.f ? x : 0.f; }

// k-slot permutation: hardware slot (g,e) holds logical channel kappa(g,e).
// Chosen so a D-fragment (lane owns rows {g*4+i} of two 16-row o-tiles) is
// directly the next layer's A/B fragment with NO cross-lane movement.
__device__ __forceinline__ int kappa(int g, int e) {
    return (e < 4) ? (g * 4 + e) : (16 + g * 4 + (e - 4));
}

// ---- prep: LDS-tiled transpose to kappa-order bf16 + BN-folded weights ----
// blocks 0..511: transpose 128-point tiles; block 512: weight folding.
__global__ __launch_bounds__(256) void prep(
    const float* __restrict__ feat,
    const float* __restrict__ w0, const float* __restrict__ g0,
    const float* __restrict__ w1, const float* __restrict__ g1,
    const float* __restrict__ w2, const float* __restrict__ g2,
    const float* __restrict__ scw, const float* __restrict__ scg,
    short* __restrict__ featTp, short* __restrict__ w0p,
    short* __restrict__ w1p, short* __restrict__ w2p, short* __restrict__ scwp)
{
    const float INVC = 0.9999950000374997f;   // 1/sqrt(1+1e-5)
    const int blk = blockIdx.x;
    if (blk < 512) {
        __shared__ float sF[32][132];          // stride 132 f32: rows 16B-aligned
        const int tid = threadIdx.x;
        const int b   = blk >> 5;
        const int p0  = (blk & 31) << 7;       // 128-point tile
        const float* fb = feat + (size_t)b * NC * NP + p0;

        // phase A: coalesced f32x4 loads, 32 c x 128 p
        #pragma unroll
        for (int i = 0; i < 4; ++i) {
            int id = tid + (i << 8);           // 1024 chunks
            int c = id >> 5, j = id & 31;
            f32x4 v = *(const f32x4*)(fb + c * NP + j * 4);
            *(f32x4*)(&sF[c][j * 4]) = v;
        }
        __syncthreads();

        // phase B: thread = (point, group); pack one bf16x8, coalesced store
        short* dstb = featTp + ((size_t)b * NP + p0) * 32;
        #pragma unroll
        for (int i = 0; i < 2; ++i) {
            int id = tid + (i << 8);           // 512 tasks
            int pl = id >> 2, g = id & 3;
            short o8[8];
            #pragma unroll
            for (int e = 0; e < 8; ++e)
                o8[e] = f2bf(sF[kappa(g, e)][pl]);
            *(bf16x8*)(dstb + pl * 32 + g * 8) = *(const bf16x8*)o8;
        }
    } else {
        const int t = threadIdx.x;
        for (int idx = t; idx < 2048; idx += 256) {        // w0p: (32 o) x (2 kc) x 32
            int o = idx >> 6, rem = idx & 63, kc = rem >> 5, pos = rem & 31;
            int g = pos >> 3, e = pos & 7;
            w0p[idx] = f2bf(w0[o * 64 + kc * 32 + kappa(g, e)] * g0[o] * INVC);
        }
        for (int idx = t; idx < 1024; idx += 256) {        // w1p: 32 x 32
            int o = idx >> 5, pos = idx & 31, g = pos >> 3, e = pos & 7;
            w1p[idx] = f2bf(w1[o * 32 + kappa(g, e)] * g1[o] * INVC);
        }
        for (int idx = t; idx < 2048; idx += 256) {        // w2p: 64 x 32
            int o = idx >> 5, pos = idx & 31, g = pos >> 3, e = pos & 7;
            w2p[idx] = f2bf(w2[o * 32 + kappa(g, e)] * g2[o] * INVC);
        }
        for (int idx = t; idx < 2048; idx += 256) {        // scwp: 64 x 32
            int o = idx >> 5, pos = idx & 31, g = pos >> 3, e = pos & 7;
            scwp[idx] = f2bf(scw[o * 32 + kappa(g, e)] * scg[o] * INVC);
        }
    }
}

// ---- main: register-resident 3-layer chain + shortcut, no barriers ----
// unroll 1 on the point loop: live set ~115 VGPR fits the 128-VGPR cap of
// (256,4) with ZERO scratch spills; latency hiding comes from 16 waves/CU.
__global__ __launch_bounds__(256, 4) void edgeconv_mfma(
    const int* __restrict__ edge, const short* __restrict__ featTp,
    const float* __restrict__ b0, const float* __restrict__ b1,
    const float* __restrict__ b2,
    const short* __restrict__ w0p, const short* __restrict__ w1p,
    const short* __restrict__ w2p, const short* __restrict__ scwp,
    const float* __restrict__ scb, float* __restrict__ out)
{
    __shared__ float sFts[4][16][68];   // [wave][pt][o], padded: conflict-free

    const int tid  = threadIdx.x;
    const int wv   = tid >> 6;
    const int lane = tid & 63;
    const int lr   = lane & 15;
    const int g    = lane >> 4;

    // XCD-contiguous swizzle: 1024 blocks, 8 XCDs, 128 blocks each
    const int bid = blockIdx.x;
    const int swz = (bid & 7) * 128 + (bid >> 3);
    const int b   = swz >> 6;                       // batch
    const int p0w = ((swz & 63) << 6) + wv * 16;    // wave's first point

    // persistent fragments (kappa-ordered weights)
    bf16x8 wA0[2][2], wA1[2], wB2[4];
    #pragma unroll
    for (int nt = 0; nt < 2; ++nt)
        #pragma unroll
        for (int kc = 0; kc < 2; ++kc)
            wA0[nt][kc] = *(const bf16x8*)(w0p + (nt * 16 + lr) * 64 + kc * 32 + g * 8);
    #pragma unroll
    for (int nt = 0; nt < 2; ++nt)
        wA1[nt] = *(const bf16x8*)(w1p + (nt * 16 + lr) * 32 + g * 8);
    #pragma unroll
    for (int nt = 0; nt < 4; ++nt)
        wB2[nt] = *(const bf16x8*)(w2p + (nt * 16 + lr) * 32 + g * 8);

    f32x4 bias0[2] = { *(const f32x4*)(b0 + g * 4), *(const f32x4*)(b0 + 16 + g * 4) };
    f32x4 bias1[2] = { *(const f32x4*)(b1 + g * 4), *(const f32x4*)(b1 + 16 + g * 4) };
    float bc2[4];
    #pragma unroll
    for (int nt = 0; nt < 4; ++nt) bc2[nt] = b2[nt * 16 + lr];

    const int*   eb = edge + (size_t)b * 2 * NE + NE;
    const short* fT = featTp + (size_t)b * NP * 32;

    #pragma unroll 1
    for (int rt = 0; rt < 16; ++rt) {
        const int p = p0w + rt;
        const int q = eb[p * K1 + lr];
        bf16x8 xf0 = *(const bf16x8*)(fT + p * 32 + g * 8);   // fp (uniform over r)
        bf16x8 fq  = *(const bf16x8*)(fT + (size_t)q * 32 + g * 8);
        bf16x8 xd;
        #pragma unroll
        for (int e = 0; e < 8; ++e) xd[e] = f2bf(bf2f(fq[e]) - bf2f(xf0[e]));

        // L0 (swapped): D0[o][r] = W0' * [fp; d]^T
        f32x4 acc0[2] = {{0.f,0.f,0.f,0.f},{0.f,0.f,0.f,0.f}};
        #pragma unroll
        for (int nt = 0; nt < 2; ++nt) {
            acc0[nt] = __builtin_amdgcn_mfma_f32_16x16x32_bf16(wA0[nt][0], xf0, acc0[nt], 0, 0, 0);
            acc0[nt] = __builtin_amdgcn_mfma_f32_16x16x32_bf16(wA0[nt][1], xd,  acc0[nt], 0, 0, 0);
        }
        // D-frag IS the next B-frag in kappa-order: bias+relu+cvt only
        bf16x8 h0;
        #pragma unroll
        for (int e = 0; e < 4; ++e) {
            h0[e]     = f2bf(relu_f(acc0[0][e] + bias0[0][e]));
            h0[e + 4] = f2bf(relu_f(acc0[1][e] + bias0[1][e]));
        }
        // L1 (swapped): D1[o][r]
        f32x4 acc1[2] = {{0.f,0.f,0.f,0.f},{0.f,0.f,0.f,0.f}};
        #pragma unroll
        for (int nt = 0; nt < 2; ++nt)
            acc1[nt] = __builtin_amdgcn_mfma_f32_16x16x32_bf16(wA1[nt], h0, acc1[nt], 0, 0, 0);
        bf16x8 h1;
        #pragma unroll
        for (int e = 0; e < 4; ++e) {
            h1[e]     = f2bf(relu_f(acc1[0][e] + bias1[0][e]));
            h1[e + 4] = f2bf(relu_f(acc1[1][e] + bias1[1][e]));
        }
        // L2 (standard): D2[r][o] — h1-frag doubles as the A operand
        f32x4 acc2[4] = {{0.f,0.f,0.f,0.f},{0.f,0.f,0.f,0.f},{0.f,0.f,0.f,0.f},{0.f,0.f,0.f,0.f}};
        #pragma unroll
        for (int nt = 0; nt < 4; ++nt)
            acc2[nt] = __builtin_amdgcn_mfma_f32_16x16x32_bf16(h1, wB2[nt], acc2[nt], 0, 0, 0);

        // relu + mean over the 16 edges (rows): local 4 + xor16 + xor32
        float f0, f1, f2, f3;
        #pragma unroll
        for (int nt = 0; nt < 4; ++nt) {
            float s = relu_f(acc2[nt][0] + bc2[nt]) + relu_f(acc2[nt][1] + bc2[nt])
                    + relu_f(acc2[nt][2] + bc2[nt]) + relu_f(acc2[nt][3] + bc2[nt]);
            s += __shfl_xor(s, 16, 64);
            s += __shfl_xor(s, 32, 64);
            if (nt == 0) f0 = s; else if (nt == 1) f1 = s; else if (nt == 2) f2 = s; else f3 = s;
        }
        float sel = (g == 0) ? f0 : (g == 1) ? f1 : (g == 2) ? f2 : f3;
        sFts[wv][rt][g * 16 + lr] = sel;   // o = g*16+lr for this lane's g
    }

    // ---- shortcut: one option-1 MFMA set over the wave's 16 points ----
    bf16x8 aS = *(const bf16x8*)(fT + (p0w + lr) * 32 + g * 8);  // rows = points
    bf16x8 wS[4];
    #pragma unroll
    for (int nt = 0; nt < 4; ++nt)
        wS[nt] = *(const bf16x8*)(scwp + (nt * 16 + lr) * 32 + g * 8);
    float scbc[4];
    #pragma unroll
    for (int nt = 0; nt < 4; ++nt) scbc[nt] = scb[nt * 16 + lr];

    f32x4 accS[4] = {{0.f,0.f,0.f,0.f},{0.f,0.f,0.f,0.f},{0.f,0.f,0.f,0.f},{0.f,0.f,0.f,0.f}};
    #pragma unroll
    for (int nt = 0; nt < 4; ++nt)
        accS[nt] = __builtin_amdgcn_mfma_f32_16x16x32_bf16(aS, wS[nt], accS[nt], 0, 0, 0);

    float* ob = out + (size_t)b * 64 * NP;
    #pragma unroll
    for (int nt = 0; nt < 4; ++nt) {
        f32x4 v;
        #pragma unroll
        for (int i = 0; i < 4; ++i) {
            float fts = sFts[wv][g * 4 + i][nt * 16 + lr];
            v[i] = relu_f(accS[nt][i] + scbc[nt] + fts * 0.0625f);
        }
        *(f32x4*)(ob + (nt * 16 + lr) * NP + p0w + g * 4) = v;
    }
}

extern "C" void kernel_launch(void* const* d_in, const int* in_sizes, int n_in,
                              void* d_out, int out_size, void* d_ws, size_t ws_size,
                              hipStream_t stream) {
    const float* feat = (const float*)d_in[1];
    const int*   edge = (const int*)d_in[2];
    const float* w0   = (const float*)d_in[3];
    const float* g0   = (const float*)d_in[4];
    const float* b0   = (const float*)d_in[5];
    const float* w1   = (const float*)d_in[6];
    const float* g1   = (const float*)d_in[7];
    const float* b1   = (const float*)d_in[8];
    const float* w2   = (const float*)d_in[9];
    const float* g2   = (const float*)d_in[10];
    const float* b2   = (const float*)d_in[11];
    const float* scw  = (const float*)d_in[12];
    const float* scg  = (const float*)d_in[13];
    const float* scb  = (const float*)d_in[14];
    float* outp = (float*)d_out;

    char* ws = (char*)d_ws;
    short* featTp = (short*)ws;                 // 16*4096*32*2 = 4,194,304 B
    short* w0p    = (short*)(ws + 4194304);     // 4096 B
    short* w1p    = (short*)(ws + 4198400);     // 2048 B
    short* w2p    = (short*)(ws + 4200448);     // 4096 B
    short* scwp   = (short*)(ws + 4204544);     // 4096 B

    prep<<<513, 256, 0, stream>>>(feat, w0, g0, w1, g1, w2, g2, scw, scg,
                                  featTp, w0p, w1p, w2p, scwp);
    edgeconv_mfma<<<1024, 256, 0, stream>>>(
        edge, featTp, b0, b1, b2, w0p, w1p, w2p, scwp, scb, outp);
}

// Round 6
// 129.238 us; speedup vs baseline: 1.0429x; 1.0320x over previous
//
#include <hip/hip_runtime.h>
#include <hip/hip_bf16.h>

#define K1 16
#define NC 32
#define NP 4096
#define NB 16
#define NE (NP * K1)

typedef __attribute__((ext_vector_type(8))) short bf16x8;
typedef __attribute__((ext_vector_type(4))) float f32x4;

__device__ __forceinline__ float bf2f(short u) {
    union { unsigned int i; float f; } x;
    x.i = ((unsigned int)(unsigned short)u) << 16;
    return x.f;
}
__device__ __forceinline__ short f2bf(float f) {
    return (short)__bfloat16_as_ushort(__float2bfloat16(f));
}
__device__ __forceinline__ float relu_f(float x) { return x > 0.f ? x : 0.f; }

// k-slot permutation: hardware slot (g,e) holds logical channel kappa(g,e).
// Chosen so a D-fragment (lane owns rows {g*4+i} of two 16-row o-tiles) is
// directly the next layer's A/B fragment with NO cross-lane movement.
__device__ __forceinline__ int kappa(int g, int e) {
    return (e < 4) ? (g * 4 + e) : (16 + g * 4 + (e - 4));
}

// ---- prep: LDS-tiled transpose to kappa-order bf16 + BN-folded weights ----
// blocks 0..511: transpose 128-point tiles; block 512: weight folding.
// w0p kc=0 now holds (W0a - W0b) folded: by linearity
//   W0a*fp + W0b*(fq-fp) = (W0a-W0b)*fp + W0b*fq  -- no per-edge subtraction.
__global__ __launch_bounds__(256) void prep(
    const float* __restrict__ feat,
    const float* __restrict__ w0, const float* __restrict__ g0,
    const float* __restrict__ w1, const float* __restrict__ g1,
    const float* __restrict__ w2, const float* __restrict__ g2,
    const float* __restrict__ scw, const float* __restrict__ scg,
    short* __restrict__ featTp, short* __restrict__ w0p,
    short* __restrict__ w1p, short* __restrict__ w2p, short* __restrict__ scwp)
{
    const float INVC = 0.9999950000374997f;   // 1/sqrt(1+1e-5)
    const int blk = blockIdx.x;
    if (blk < 512) {
        __shared__ float sF[32][132];          // stride 132 f32: rows 16B-aligned
        const int tid = threadIdx.x;
        const int b   = blk >> 5;
        const int p0  = (blk & 31) << 7;       // 128-point tile
        const float* fb = feat + (size_t)b * NC * NP + p0;

        // phase A: coalesced f32x4 loads, 32 c x 128 p
        #pragma unroll
        for (int i = 0; i < 4; ++i) {
            int id = tid + (i << 8);           // 1024 chunks
            int c = id >> 5, j = id & 31;
            f32x4 v = *(const f32x4*)(fb + c * NP + j * 4);
            *(f32x4*)(&sF[c][j * 4]) = v;
        }
        __syncthreads();

        // phase B: thread = (point, group); pack one bf16x8, coalesced store
        short* dstb = featTp + ((size_t)b * NP + p0) * 32;
        #pragma unroll
        for (int i = 0; i < 2; ++i) {
            int id = tid + (i << 8);           // 512 tasks
            int pl = id >> 2, g = id & 3;
            short o8[8];
            #pragma unroll
            for (int e = 0; e < 8; ++e)
                o8[e] = f2bf(sF[kappa(g, e)][pl]);
            *(bf16x8*)(dstb + pl * 32 + g * 8) = *(const bf16x8*)o8;
        }
    } else {
        const int t = threadIdx.x;
        for (int idx = t; idx < 2048; idx += 256) {        // w0p: (32 o) x (2 kc) x 32
            int o = idx >> 6, rem = idx & 63, kc = rem >> 5, pos = rem & 31;
            int g = pos >> 3, e = pos & 7;
            float wa = w0[o * 64 + kappa(g, e)];           // fp-part weight
            float wb = w0[o * 64 + 32 + kappa(g, e)];      // d-part weight
            float v  = (kc == 0) ? (wa - wb) : wb;
            w0p[idx] = f2bf(v * g0[o] * INVC);
        }
        for (int idx = t; idx < 1024; idx += 256) {        // w1p: 32 x 32
            int o = idx >> 5, pos = idx & 31, g = pos >> 3, e = pos & 7;
            w1p[idx] = f2bf(w1[o * 32 + kappa(g, e)] * g1[o] * INVC);
        }
        for (int idx = t; idx < 2048; idx += 256) {        // w2p: 64 x 32
            int o = idx >> 5, pos = idx & 31, g = pos >> 3, e = pos & 7;
            w2p[idx] = f2bf(w2[o * 32 + kappa(g, e)] * g2[o] * INVC);
        }
        for (int idx = t; idx < 2048; idx += 256) {        // scwp: 64 x 32
            int o = idx >> 5, pos = idx & 31, g = pos >> 3, e = pos & 7;
            scwp[idx] = f2bf(scw[o * 32 + kappa(g, e)] * scg[o] * INVC);
        }
    }
}

// ---- main: register-resident 3-layer chain + shortcut, no barriers ----
__global__ __launch_bounds__(256, 4) void edgeconv_mfma(
    const int* __restrict__ edge, const short* __restrict__ featTp,
    const float* __restrict__ b0, const float* __restrict__ b1,
    const float* __restrict__ b2,
    const short* __restrict__ w0p, const short* __restrict__ w1p,
    const short* __restrict__ w2p, const short* __restrict__ scwp,
    const float* __restrict__ scb, float* __restrict__ out)
{
    __shared__ float sFts[4][16][68];   // [wave][pt][o], padded: conflict-free

    const int tid  = threadIdx.x;
    const int wv   = tid >> 6;
    const int lane = tid & 63;
    const int lr   = lane & 15;
    const int g    = lane >> 4;

    // XCD-contiguous swizzle: 1024 blocks, 8 XCDs, 128 blocks each
    const int bid = blockIdx.x;
    const int swz = (bid & 7) * 128 + (bid >> 3);
    const int b   = swz >> 6;                       // batch
    const int p0w = ((swz & 63) << 6) + wv * 16;    // wave's first point

    // persistent fragments (kappa-ordered weights)
    bf16x8 wA0[2][2], wA1[2], wB2[4];
    #pragma unroll
    for (int nt = 0; nt < 2; ++nt)
        #pragma unroll
        for (int kc = 0; kc < 2; ++kc)
            wA0[nt][kc] = *(const bf16x8*)(w0p + (nt * 16 + lr) * 64 + kc * 32 + g * 8);
    #pragma unroll
    for (int nt = 0; nt < 2; ++nt)
        wA1[nt] = *(const bf16x8*)(w1p + (nt * 16 + lr) * 32 + g * 8);
    #pragma unroll
    for (int nt = 0; nt < 4; ++nt)
        wB2[nt] = *(const bf16x8*)(w2p + (nt * 16 + lr) * 32 + g * 8);

    f32x4 bias0[2] = { *(const f32x4*)(b0 + g * 4), *(const f32x4*)(b0 + 16 + g * 4) };
    f32x4 bias1[2] = { *(const f32x4*)(b1 + g * 4), *(const f32x4*)(b1 + 16 + g * 4) };
    float bc2[4];
    #pragma unroll
    for (int nt = 0; nt < 4; ++nt) bc2[nt] = b2[nt * 16 + lr];

    const int*   eb = edge + (size_t)b * 2 * NE + NE;
    const short* fT = featTp + (size_t)b * NP * 32;

    // edge-index prefetch: break the eb->q->fq dependent-load chain
    int q_pref = eb[p0w * K1 + lr];

    #pragma unroll 1
    for (int rt = 0; rt < 16; ++rt) {
        const int p = p0w + rt;
        const int q = q_pref;
        const int rtn = (rt < 15) ? (rt + 1) : 15;      // clamp: no OOB on last
        q_pref = eb[(p0w + rtn) * K1 + lr];

        bf16x8 xf0 = *(const bf16x8*)(fT + p * 32 + g * 8);        // fp (uniform)
        bf16x8 fq  = *(const bf16x8*)(fT + (size_t)q * 32 + g * 8); // gathered

        // L0 (swapped): D0[o][r] = (W0a-W0b)'*fp + W0b'*fq  — no xd needed
        f32x4 acc0[2] = {{0.f,0.f,0.f,0.f},{0.f,0.f,0.f,0.f}};
        #pragma unroll
        for (int nt = 0; nt < 2; ++nt) {
            acc0[nt] = __builtin_amdgcn_mfma_f32_16x16x32_bf16(wA0[nt][0], xf0, acc0[nt], 0, 0, 0);
            acc0[nt] = __builtin_amdgcn_mfma_f32_16x16x32_bf16(wA0[nt][1], fq,  acc0[nt], 0, 0, 0);
        }
        // D-frag IS the next B-frag in kappa-order: bias+relu+cvt only
        bf16x8 h0;
        #pragma unroll
        for (int e = 0; e < 4; ++e) {
            h0[e]     = f2bf(relu_f(acc0[0][e] + bias0[0][e]));
            h0[e + 4] = f2bf(relu_f(acc0[1][e] + bias0[1][e]));
        }
        // L1 (swapped): D1[o][r]
        f32x4 acc1[2] = {{0.f,0.f,0.f,0.f},{0.f,0.f,0.f,0.f}};
        #pragma unroll
        for (int nt = 0; nt < 2; ++nt)
            acc1[nt] = __builtin_amdgcn_mfma_f32_16x16x32_bf16(wA1[nt], h0, acc1[nt], 0, 0, 0);
        bf16x8 h1;
        #pragma unroll
        for (int e = 0; e < 4; ++e) {
            h1[e]     = f2bf(relu_f(acc1[0][e] + bias1[0][e]));
            h1[e + 4] = f2bf(relu_f(acc1[1][e] + bias1[1][e]));
        }
        // L2 (standard): D2[r][o] — h1-frag doubles as the A operand
        f32x4 acc2[4] = {{0.f,0.f,0.f,0.f},{0.f,0.f,0.f,0.f},{0.f,0.f,0.f,0.f},{0.f,0.f,0.f,0.f}};
        #pragma unroll
        for (int nt = 0; nt < 4; ++nt)
            acc2[nt] = __builtin_amdgcn_mfma_f32_16x16x32_bf16(h1, wB2[nt], acc2[nt], 0, 0, 0);

        // relu + mean over the 16 edges (rows): local 4 + xor16 + xor32
        float f0, f1, f2, f3;
        #pragma unroll
        for (int nt = 0; nt < 4; ++nt) {
            float s = relu_f(acc2[nt][0] + bc2[nt]) + relu_f(acc2[nt][1] + bc2[nt])
                    + relu_f(acc2[nt][2] + bc2[nt]) + relu_f(acc2[nt][3] + bc2[nt]);
            s += __shfl_xor(s, 16, 64);
            s += __shfl_xor(s, 32, 64);
            if (nt == 0) f0 = s; else if (nt == 1) f1 = s; else if (nt == 2) f2 = s; else f3 = s;
        }
        float sel = (g == 0) ? f0 : (g == 1) ? f1 : (g == 2) ? f2 : f3;
        sFts[wv][rt][g * 16 + lr] = sel;   // o = g*16+lr for this lane's g
    }

    // ---- shortcut: one option-1 MFMA set over the wave's 16 points ----
    bf16x8 aS = *(const bf16x8*)(fT + (p0w + lr) * 32 + g * 8);  // rows = points
    bf16x8 wS[4];
    #pragma unroll
    for (int nt = 0; nt < 4; ++nt)
        wS[nt] = *(const bf16x8*)(scwp + (nt * 16 + lr) * 32 + g * 8);
    float scbc[4];
    #pragma unroll
    for (int nt = 0; nt < 4; ++nt) scbc[nt] = scb[nt * 16 + lr];

    f32x4 accS[4] = {{0.f,0.f,0.f,0.f},{0.f,0.f,0.f,0.f},{0.f,0.f,0.f,0.f},{0.f,0.f,0.f,0.f}};
    #pragma unroll
    for (int nt = 0; nt < 4; ++nt)
        accS[nt] = __builtin_amdgcn_mfma_f32_16x16x32_bf16(aS, wS[nt], accS[nt], 0, 0, 0);

    float* ob = out + (size_t)b * 64 * NP;
    #pragma unroll
    for (int nt = 0; nt < 4; ++nt) {
        f32x4 v;
        #pragma unroll
        for (int i = 0; i < 4; ++i) {
            float fts = sFts[wv][g * 4 + i][nt * 16 + lr];
            v[i] = relu_f(accS[nt][i] + scbc[nt] + fts * 0.0625f);
        }
        *(f32x4*)(ob + (nt * 16 + lr) * NP + p0w + g * 4) = v;
    }
}

extern "C" void kernel_launch(void* const* d_in, const int* in_sizes, int n_in,
                              void* d_out, int out_size, void* d_ws, size_t ws_size,
                              hipStream_t stream) {
    const float* feat = (const float*)d_in[1];
    const int*   edge = (const int*)d_in[2];
    const float* w0   = (const float*)d_in[3];
    const float* g0   = (const float*)d_in[4];
    const float* b0   = (const float*)d_in[5];
    const float* w1   = (const float*)d_in[6];
    const float* g1   = (const float*)d_in[7];
    const float* b1   = (const float*)d_in[8];
    const float* w2   = (const float*)d_in[9];
    const float* g2   = (const float*)d_in[10];
    const float* b2   = (const float*)d_in[11];
    const float* scw  = (const float*)d_in[12];
    const float* scg  = (const float*)d_in[13];
    const float* scb  = (const float*)d_in[14];
    float* outp = (float*)d_out;

    char* ws = (char*)d_ws;
    short* featTp = (short*)ws;                 // 16*4096*32*2 = 4,194,304 B
    short* w0p    = (short*)(ws + 4194304);     // 4096 B
    short* w1p    = (short*)(ws + 4198400);     // 2048 B
    short* w2p    = (short*)(ws + 4200448);     // 4096 B
    short* scwp   = (short*)(ws + 4204544);     // 4096 B

    prep<<<513, 256, 0, stream>>>(feat, w0, g0, w1, g1, w2, g2, scw, scg,
                                  featTp, w0p, w1p, w2p, scwp);
    edgeconv_mfma<<<1024, 256, 0, stream>>>(
        edge, featTp, b0, b1, b2, w0p, w1p, w2p, scwp, scb, outp);
}